// Round 2
// baseline (3722.318 us; speedup 1.0000x reference)
//
#include <hip/hip_runtime.h>
#include <hip/hip_bf16.h>

// SelfAttention (SAGAN) block, B=16 H=64 W=64 C=512, c8=64, c2=256.
// Input dtype (bf16 vs f32) is detected at runtime from x's bit patterns;
// all kernels are templated on it and early-exit on flag mismatch.
//
// Workspace layout (bytes), total 20,186,112:
//   0        : dtype flag (int; 1 = float32, 0 = bf16)
//   1024     : w_theta fp32 [512][64]
//   132096   : w_phi   fp32 [512][64]
//   263168   : w_g     fp32 [512][256]
//   787456   : w_attn  fp32 [256][512]
//   1311744  : theta   bf16 [16][4096][64]
//   9700352  : phi     bf16 [16][1024][64]
//   11797504 : g       bf16 [16][1024][256]

using bf16 = __hip_bfloat16;

#define WS_FLAG   0
#define WS_WT     1024
#define WS_WP     132096
#define WS_WG     263168
#define WS_WA     787456
#define WS_THETA  1311744
#define WS_PHI    9700352
#define WS_G      11797504
#define WS_TOTAL  20186112

__device__ __forceinline__ float bf2f(bf16 v) { return __bfloat162float(v); }
__device__ __forceinline__ bf16 f2bf(float v) { return __float2bfloat16(v); }

__device__ __forceinline__ void unpack8(uint4 p, float* f) {
  f[0] = __uint_as_float(p.x << 16);
  f[1] = __uint_as_float(p.x & 0xffff0000u);
  f[2] = __uint_as_float(p.y << 16);
  f[3] = __uint_as_float(p.y & 0xffff0000u);
  f[4] = __uint_as_float(p.z << 16);
  f[5] = __uint_as_float(p.z & 0xffff0000u);
  f[6] = __uint_as_float(p.w << 16);
  f[7] = __uint_as_float(p.w & 0xffff0000u);
}

// 8-contiguous-element bf16 load from workspace intermediates (always bf16)
__device__ __forceinline__ void ld8_bf(const bf16* p, float* f) {
  unpack8(*(const uint4*)p, f);
}

template <typename T> struct io;
template <> struct io<bf16> {
  static __device__ __forceinline__ float ld(const bf16* p) { return bf2f(*p); }
  static __device__ __forceinline__ void ld8(const bf16* p, float* f) { unpack8(*(const uint4*)p, f); }
  static __device__ __forceinline__ void st(bf16* p, float v) { *p = f2bf(v); }
  static __device__ __forceinline__ int tag() { return 0; }
};
template <> struct io<float> {
  static __device__ __forceinline__ float ld(const float* p) { return *p; }
  static __device__ __forceinline__ void ld8(const float* p, float* f) {
    float4 a = *(const float4*)p; float4 b = *(const float4*)(p + 4);
    f[0] = a.x; f[1] = a.y; f[2] = a.z; f[3] = a.w;
    f[4] = b.x; f[5] = b.y; f[6] = b.z; f[7] = b.w;
  }
  static __device__ __forceinline__ void st(float* p, float v) { *p = v; }
  static __device__ __forceinline__ int tag() { return 1; }
};

// --------------- Kernel 0: detect input storage dtype ----------------------
// If x is stored f32, its mantissa uint16 words hit the bf16 NaN/Inf pattern
// (~0.4% of words). If stored bf16, zero hits (x is finite N(0,1)).
__global__ __launch_bounds__(256) void detect_kernel(const void* xraw, int* flag) {
  const unsigned short* p = (const unsigned short*)xraw;
  int t = threadIdx.x;
  int cnt = 0;
  for (int i = t; i < 65536; i += 256) {
    unsigned short v = p[i];
    if ((v & 0x7F80u) == 0x7F80u) cnt++;
  }
#pragma unroll
  for (int o = 32; o > 0; o >>= 1) cnt += __shfl_down(cnt, o, 64);
  __shared__ int red[4];
  if ((t & 63) == 0) red[t >> 6] = cnt;
  __syncthreads();
  if (t == 0) flag[0] = (red[0] + red[1] + red[2] + red[3] > 4) ? 1 : 0;
}

__device__ __forceinline__ float block_sum_256(float x, float* red) {
#pragma unroll
  for (int o = 32; o > 0; o >>= 1) x += __shfl_down(x, o, 64);
  __syncthreads();
  if ((threadIdx.x & 63) == 0) red[threadIdx.x >> 6] = x;
  __syncthreads();
  return red[0] + red[1] + red[2] + red[3];
}

// ---------------- Kernel 1: spectral norm of all 4 weights -----------------
// sigma = ||t2||^2/(||t2||+eps), t2 = v@w, v = t1/(||t1||+eps), t1 = u@w^T
template <typename T>
__global__ __launch_bounds__(256) void sn_kernel(
    const void* ktv, const void* utv, const void* kpv, const void* upv,
    const void* kgv, const void* ugv, const void* kav, const void* uav,
    float* wt, float* wp, float* wg, float* wa, const int* flag) {
  if (flag[0] != io<T>::tag()) return;
  __shared__ float v[512];
  __shared__ float red[4];
  const T* w; const T* u; float* out; int cin, cout;
  switch (blockIdx.x) {
    case 0:  w = (const T*)ktv; u = (const T*)utv; out = wt; cin = 512; cout = 64;  break;
    case 1:  w = (const T*)kpv; u = (const T*)upv; out = wp; cin = 512; cout = 64;  break;
    case 2:  w = (const T*)kgv; u = (const T*)ugv; out = wg; cin = 512; cout = 256; break;
    default: w = (const T*)kav; u = (const T*)uav; out = wa; cin = 256; cout = 512; break;
  }
  int t = threadIdx.x;
  float loc = 0.f;
  for (int i = t; i < cin; i += 256) {
    float acc = 0.f;
    const T* wr = w + (size_t)i * cout;
    for (int j = 0; j < cout; ++j) acc += io<T>::ld(u + j) * io<T>::ld(wr + j);
    v[i] = acc;
    loc += acc * acc;
  }
  float s1 = block_sum_256(loc, red);
  float inv1 = 1.f / (sqrtf(s1) + 1e-12f);
  float loc2 = 0.f;
  for (int j = t; j < cout; j += 256) {
    float acc = 0.f;
    for (int i = 0; i < cin; ++i) acc += v[i] * io<T>::ld(w + (size_t)i * cout + j);
    acc *= inv1;
    loc2 += acc * acc;
  }
  float s2 = block_sum_256(loc2, red);
  float sigma = s2 / (sqrtf(s2) + 1e-12f);
  float winv = 1.f / sigma;
  int total = cin * cout;
  for (int k = t; k < total; k += 256) out[k] = io<T>::ld(w + k) * winv;
}

// ------------- Kernel 2: fused theta/phi/g convs + 2x2 maxpool -------------
template <typename T>
__global__ __launch_bounds__(256) void conv3_kernel(
    const void* xv,
    const float* __restrict__ wt, const float* __restrict__ wp,
    const float* __restrict__ wg,
    bf16* __restrict__ theta, bf16* __restrict__ phi, bf16* __restrict__ g,
    const int* flag) {
  if (flag[0] != io<T>::tag()) return;
  const T* x = (const T*)xv;
  __shared__ float xs[4][512];
  __shared__ float pred[4][64];
  int idx = blockIdx.x;
  int b = idx >> 10;
  int rem = idx & 1023;
  int ph = rem >> 5, pw = rem & 31;
  int t = threadIdx.x;
  {
    int e = t * 8;                 // 2048 elements / 256 threads
    int p = e >> 9, c = e & 511;
    int dh = p >> 1, dw = p & 1;
    size_t off = (((size_t)(b * 64 + 2 * ph + dh)) * 64 + (2 * pw + dw)) * 512 + c;
    io<T>::ld8(x + off, &xs[p][c]);
  }
  __syncthreads();
  int pp = t >> 6, co = t & 63;
  int dh = pp >> 1, dw = pp & 1;
  {
    float acc = 0.f;
#pragma unroll 8
    for (int ci = 0; ci < 512; ++ci) acc += xs[pp][ci] * wt[ci * 64 + co];
    int n = (2 * ph + dh) * 64 + (2 * pw + dw);
    theta[((size_t)b * 4096 + n) * 64 + co] = f2bf(acc);
  }
  {
    float acc = 0.f;
#pragma unroll 8
    for (int ci = 0; ci < 512; ++ci) acc += xs[pp][ci] * wp[ci * 64 + co];
    pred[pp][co] = acc;
  }
  __syncthreads();
  if (pp == 0) {
    float m = fmaxf(fmaxf(pred[0][co], pred[1][co]), fmaxf(pred[2][co], pred[3][co]));
    phi[((size_t)b * 1024 + ph * 32 + pw) * 64 + co] = f2bf(m);
  }
  {
    int cog = t;
    float a0 = 0.f, a1 = 0.f, a2 = 0.f, a3 = 0.f;
#pragma unroll 4
    for (int ci = 0; ci < 512; ++ci) {
      float wv = wg[ci * 256 + cog];
      a0 += xs[0][ci] * wv; a1 += xs[1][ci] * wv;
      a2 += xs[2][ci] * wv; a3 += xs[3][ci] * wv;
    }
    float m = fmaxf(fmaxf(a0, a1), fmaxf(a2, a3));
    g[((size_t)b * 1024 + ph * 32 + pw) * 256 + cog] = f2bf(m);
  }
}

// ---- Kernel 3: attention (QK^T -> softmax -> @g) + output proj + residual ---
// Block = 8 queries x 32 threads. All 1024 logits per query in LDS.
// attnO rows stay in LDS (never hit HBM); proj + residual fused here.
template <typename T>
__global__ __launch_bounds__(256) void attnproj_kernel(
    const bf16* __restrict__ theta, const bf16* __restrict__ phi,
    const bf16* __restrict__ g, const float* __restrict__ wa,
    const void* xv, const void* sigv, void* outv, const int* flag) {
  if (flag[0] != io<T>::tag()) return;
  const T* xp = (const T*)xv;
  T* outp = (T*)outv;
  __shared__ float th[8][72];
  __shared__ float L[8][1040];     // stride%32==16 -> worst 2-way (free)
  __shared__ float red[8][32];
  __shared__ float mx[8];
  __shared__ float dinv[8];
  __shared__ float ao[8][256];
  int blk = blockIdx.x;
  int b = blk >> 9;
  int q0 = (blk & 511) * 8;
  int t = threadIdx.x;
  for (int k = t; k < 8 * 64; k += 256) {
    int qq = k >> 6, c = k & 63;
    th[qq][c] = bf2f(theta[((size_t)b * 4096 + q0 + qq) * 64 + c]);
  }
  __syncthreads();
  int q = t >> 5, s = t & 31;
  const bf16* phib = phi + (size_t)b * 1024 * 64;
  for (int mb = 0; mb < 32; ++mb) {
    int m = mb * 32 + s;
    const bf16* pr = phib + (size_t)m * 64;
    float acc = 0.f;
#pragma unroll
    for (int c = 0; c < 64; c += 8) {
      float f[8]; ld8_bf(pr + c, f);
      acc += f[0] * th[q][c + 0] + f[1] * th[q][c + 1] +
             f[2] * th[q][c + 2] + f[3] * th[q][c + 3] +
             f[4] * th[q][c + 4] + f[5] * th[q][c + 5] +
             f[6] * th[q][c + 6] + f[7] * th[q][c + 7];
    }
    L[q][m] = acc;
  }
  __syncthreads();
  float pmax = -1e30f;
  for (int mb = 0; mb < 32; ++mb) pmax = fmaxf(pmax, L[q][mb * 32 + s]);
  red[q][s] = pmax;
  __syncthreads();
  if (s == 0) {
    float mv = red[q][0];
    for (int k = 1; k < 32; ++k) mv = fmaxf(mv, red[q][k]);
    mx[q] = mv;
  }
  __syncthreads();
  float mval = mx[q];
  float psum = 0.f;
  for (int mb = 0; mb < 32; ++mb) {
    int m = mb * 32 + s;
    float e = __expf(L[q][m] - mval);
    L[q][m] = e;
    psum += e;
  }
  red[q][s] = psum;
  __syncthreads();
  if (s == 0) {
    float sum = 0.f;
    for (int k = 0; k < 32; ++k) sum += red[q][k];
    dinv[q] = 1.f / sum;
  }
  __syncthreads();
  // PV: each thread: 8 output channels for its query over all 1024 keys
  const bf16* gb = g + (size_t)b * 1024 * 256;
  int cb = s * 8;
  float acc[8];
#pragma unroll
  for (int k = 0; k < 8; ++k) acc[k] = 0.f;
  for (int m = 0; m < 1024; ++m) {
    float p = L[q][m];
    float f[8]; ld8_bf(gb + (size_t)m * 256 + cb, f);
#pragma unroll
    for (int k = 0; k < 8; ++k) acc[k] += p * f[k];
  }
  float di = dinv[q];
#pragma unroll
  for (int k = 0; k < 8; ++k) ao[q][cb + k] = acc[k] * di;
  __syncthreads();
  // Output projection: rows q0..q0+7, 512 couts; wa [256][512] coalesced
  float pa[16];
#pragma unroll
  for (int k = 0; k < 16; ++k) pa[k] = 0.f;
  int co0 = t, co1 = t + 256;
  for (int ci = 0; ci < 256; ++ci) {
    float w0 = wa[ci * 512 + co0];
    float w1 = wa[ci * 512 + co1];
#pragma unroll
    for (int qq = 0; qq < 8; ++qq) {
      pa[qq] += ao[qq][ci] * w0;
      pa[qq + 8] += ao[qq][ci] * w1;
    }
  }
  float sgv = io<T>::ld((const T*)sigv);
#pragma unroll
  for (int qq = 0; qq < 8; ++qq) {
    size_t off = ((size_t)b * 4096 + q0 + qq) * 512;
    io<T>::st(outp + off + co0, io<T>::ld(xp + off + co0) + sgv * pa[qq]);
    io<T>::st(outp + off + co1, io<T>::ld(xp + off + co1) + sgv * pa[qq + 8]);
  }
}

extern "C" void kernel_launch(void* const* d_in, const int* in_sizes, int n_in,
                              void* d_out, int out_size, void* d_ws, size_t ws_size,
                              hipStream_t stream) {
  if (ws_size < (size_t)WS_TOTAL) return;  // distinguishable failure: out stays 0
  char* ws = (char*)d_ws;
  int*   flag  = (int*)(ws + WS_FLAG);
  float* wt    = (float*)(ws + WS_WT);
  float* wp    = (float*)(ws + WS_WP);
  float* wg    = (float*)(ws + WS_WG);
  float* wa    = (float*)(ws + WS_WA);
  bf16*  theta = (bf16*)(ws + WS_THETA);
  bf16*  phi   = (bf16*)(ws + WS_PHI);
  bf16*  g     = (bf16*)(ws + WS_G);

  detect_kernel<<<1, 256, 0, stream>>>(d_in[0], flag);

  sn_kernel<bf16><<<4, 256, 0, stream>>>(d_in[1], d_in[2], d_in[3], d_in[4],
                                         d_in[5], d_in[6], d_in[7], d_in[8],
                                         wt, wp, wg, wa, flag);
  sn_kernel<float><<<4, 256, 0, stream>>>(d_in[1], d_in[2], d_in[3], d_in[4],
                                          d_in[5], d_in[6], d_in[7], d_in[8],
                                          wt, wp, wg, wa, flag);

  conv3_kernel<bf16><<<16384, 256, 0, stream>>>(d_in[0], wt, wp, wg, theta, phi, g, flag);
  conv3_kernel<float><<<16384, 256, 0, stream>>>(d_in[0], wt, wp, wg, theta, phi, g, flag);

  attnproj_kernel<bf16><<<8192, 256, 0, stream>>>(theta, phi, g, wa, d_in[0], d_in[9], d_out, flag);
  attnproj_kernel<float><<<8192, 256, 0, stream>>>(theta, phi, g, wa, d_in[0], d_in[9], d_out, flag);
}

// Round 3
// 1765.949 us; speedup vs baseline: 2.1078x; 2.1078x over previous
//
#include <hip/hip_runtime.h>
#include <hip/hip_bf16.h>

// SelfAttention (SAGAN) block, B=16 H=64 W=64 C=512, c8=64, c2=256.
// Input storage dtype (bf16 vs f32) detected at runtime; kernels templated.
//
// Workspace layout (bytes), total 20,448,256:
//   0        : dtype flag (int; 1 = float32, 0 = bf16)
//   1024     : w_theta fp32 [512][64]
//   132096   : w_phi   fp32 [512][64]
//   263168   : w_g     fp32 [512][256]
//   787456   : w_attn  fp32 [256][512]   (unused by attnproj now; kept)
//   1311744  : theta   bf16 [16][4096][64]
//   9700352  : phi     bf16 [16][1024][64]
//   11797504 : g       bf16 [16][1024][256]
//   20186112 : waT     bf16 [512][256]   (transposed normalized k_attn)

using bf16 = __hip_bfloat16;
typedef unsigned short u16;
typedef __attribute__((ext_vector_type(8))) short bf16x8;  // 8 bf16 = 4 VGPRs
typedef __attribute__((ext_vector_type(4))) float f32x4;

#define MFMA16(a, b, c) __builtin_amdgcn_mfma_f32_16x16x32_bf16((a), (b), (c), 0, 0, 0)

#define WS_FLAG   0
#define WS_WT     1024
#define WS_WP     132096
#define WS_WG     263168
#define WS_WA     787456
#define WS_THETA  1311744
#define WS_PHI    9700352
#define WS_G      11797504
#define WS_WAT    20186112
#define WS_TOTAL  20448256

__device__ __forceinline__ float bf2f(bf16 v) { return __bfloat162float(v); }
__device__ __forceinline__ bf16 f2bf(float v) { return __float2bfloat16(v); }
__device__ __forceinline__ u16 f2bf_bits(float v) { bf16 h = f2bf(v); return *(u16*)&h; }

__device__ __forceinline__ void unpack8(uint4 p, float* f) {
  f[0] = __uint_as_float(p.x << 16);
  f[1] = __uint_as_float(p.x & 0xffff0000u);
  f[2] = __uint_as_float(p.y << 16);
  f[3] = __uint_as_float(p.y & 0xffff0000u);
  f[4] = __uint_as_float(p.z << 16);
  f[5] = __uint_as_float(p.z & 0xffff0000u);
  f[6] = __uint_as_float(p.w << 16);
  f[7] = __uint_as_float(p.w & 0xffff0000u);
}

template <typename T> struct io;
template <> struct io<bf16> {
  static __device__ __forceinline__ float ld(const bf16* p) { return bf2f(*p); }
  static __device__ __forceinline__ void ld8(const bf16* p, float* f) { unpack8(*(const uint4*)p, f); }
  static __device__ __forceinline__ void st(bf16* p, float v) { *p = f2bf(v); }
  static __device__ __forceinline__ int tag() { return 0; }
};
template <> struct io<float> {
  static __device__ __forceinline__ float ld(const float* p) { return *p; }
  static __device__ __forceinline__ void ld8(const float* p, float* f) {
    float4 a = *(const float4*)p; float4 b = *(const float4*)(p + 4);
    f[0] = a.x; f[1] = a.y; f[2] = a.z; f[3] = a.w;
    f[4] = b.x; f[5] = b.y; f[6] = b.z; f[7] = b.w;
  }
  static __device__ __forceinline__ void st(float* p, float v) { *p = v; }
  static __device__ __forceinline__ int tag() { return 1; }
};

// --------------- Kernel 0: detect input storage dtype ----------------------
__global__ __launch_bounds__(256) void detect_kernel(const void* xraw, int* flag) {
  const u16* p = (const u16*)xraw;
  int t = threadIdx.x;
  int cnt = 0;
  for (int i = t; i < 65536; i += 256) {
    u16 v = p[i];
    if ((v & 0x7F80u) == 0x7F80u) cnt++;
  }
#pragma unroll
  for (int o = 32; o > 0; o >>= 1) cnt += __shfl_down(cnt, o, 64);
  __shared__ int red[4];
  if ((t & 63) == 0) red[t >> 6] = cnt;
  __syncthreads();
  if (t == 0) flag[0] = (red[0] + red[1] + red[2] + red[3] > 4) ? 1 : 0;
}

__device__ __forceinline__ float block_sum_256(float x, float* red) {
#pragma unroll
  for (int o = 32; o > 0; o >>= 1) x += __shfl_down(x, o, 64);
  __syncthreads();
  if ((threadIdx.x & 63) == 0) red[threadIdx.x >> 6] = x;
  __syncthreads();
  return red[0] + red[1] + red[2] + red[3];
}

// ---------------- Kernel 1: spectral norm of all 4 weights -----------------
template <typename T>
__global__ __launch_bounds__(256) void sn_kernel(
    const void* ktv, const void* utv, const void* kpv, const void* upv,
    const void* kgv, const void* ugv, const void* kav, const void* uav,
    float* wt, float* wp, float* wg, float* wa, u16* waT, const int* flag) {
  if (flag[0] != io<T>::tag()) return;
  __shared__ float v[512];
  __shared__ float red[4];
  const T* w; const T* u; float* out; int cin, cout;
  switch (blockIdx.x) {
    case 0:  w = (const T*)ktv; u = (const T*)utv; out = wt; cin = 512; cout = 64;  break;
    case 1:  w = (const T*)kpv; u = (const T*)upv; out = wp; cin = 512; cout = 64;  break;
    case 2:  w = (const T*)kgv; u = (const T*)ugv; out = wg; cin = 512; cout = 256; break;
    default: w = (const T*)kav; u = (const T*)uav; out = wa; cin = 256; cout = 512; break;
  }
  int t = threadIdx.x;
  float loc = 0.f;
  for (int i = t; i < cin; i += 256) {
    float acc = 0.f;
    const T* wr = w + (size_t)i * cout;
    for (int j = 0; j < cout; ++j) acc += io<T>::ld(u + j) * io<T>::ld(wr + j);
    v[i] = acc;
    loc += acc * acc;
  }
  float s1 = block_sum_256(loc, red);
  float inv1 = 1.f / (sqrtf(s1) + 1e-12f);
  float loc2 = 0.f;
  for (int j = t; j < cout; j += 256) {
    float acc = 0.f;
    for (int i = 0; i < cin; ++i) acc += v[i] * io<T>::ld(w + (size_t)i * cout + j);
    acc *= inv1;
    loc2 += acc * acc;
  }
  float s2 = block_sum_256(loc2, red);
  float sigma = s2 / (sqrtf(s2) + 1e-12f);
  float winv = 1.f / sigma;
  int total = cin * cout;
  bool isA = (blockIdx.x == 3);
  for (int k = t; k < total; k += 256) {
    float val = io<T>::ld(w + k) * winv;
    out[k] = val;
    if (isA) {                       // also write bf16 transposed copy [512][256]
      int i = k >> 9, j = k & 511;
      waT[j * 256 + i] = f2bf_bits(val);
    }
  }
}

// ------------- Kernel 2: fused theta/phi/g convs + 2x2 maxpool -------------
template <typename T>
__global__ __launch_bounds__(256) void conv3_kernel(
    const void* xv,
    const float* __restrict__ wt, const float* __restrict__ wp,
    const float* __restrict__ wg,
    bf16* __restrict__ theta, bf16* __restrict__ phi, bf16* __restrict__ g,
    const int* flag) {
  if (flag[0] != io<T>::tag()) return;
  const T* x = (const T*)xv;
  __shared__ float xs[4][512];
  __shared__ float pred[4][64];
  int idx = blockIdx.x;
  int bb = idx >> 10;
  int rem = idx & 1023;
  int ph = rem >> 5, pw = rem & 31;
  int t = threadIdx.x;
  {
    int e = t * 8;
    int p = e >> 9, c = e & 511;
    int dh = p >> 1, dw = p & 1;
    size_t off = (((size_t)(bb * 64 + 2 * ph + dh)) * 64 + (2 * pw + dw)) * 512 + c;
    io<T>::ld8(x + off, &xs[p][c]);
  }
  __syncthreads();
  int pp = t >> 6, co = t & 63;
  int dh = pp >> 1, dw = pp & 1;
  {
    float acc = 0.f;
#pragma unroll 8
    for (int ci = 0; ci < 512; ++ci) acc += xs[pp][ci] * wt[ci * 64 + co];
    int n = (2 * ph + dh) * 64 + (2 * pw + dw);
    theta[((size_t)bb * 4096 + n) * 64 + co] = f2bf(acc);
  }
  {
    float acc = 0.f;
#pragma unroll 8
    for (int ci = 0; ci < 512; ++ci) acc += xs[pp][ci] * wp[ci * 64 + co];
    pred[pp][co] = acc;
  }
  __syncthreads();
  if (pp == 0) {
    float m = fmaxf(fmaxf(pred[0][co], pred[1][co]), fmaxf(pred[2][co], pred[3][co]));
    phi[((size_t)bb * 1024 + ph * 32 + pw) * 64 + co] = f2bf(m);
  }
  {
    int cog = t;
    float a0 = 0.f, a1 = 0.f, a2 = 0.f, a3 = 0.f;
#pragma unroll 4
    for (int ci = 0; ci < 512; ++ci) {
      float wv = wg[ci * 256 + cog];
      a0 += xs[0][ci] * wv; a1 += xs[1][ci] * wv;
      a2 += xs[2][ci] * wv; a3 += xs[3][ci] * wv;
    }
    float m = fmaxf(fmaxf(a0, a1), fmaxf(a2, a3));
    g[((size_t)bb * 1024 + ph * 32 + pw) * 256 + cog] = f2bf(m);
  }
}

// ---- Kernel 3: MFMA attention (QK^T -> online softmax -> @g) + proj + res ---
// Block = 4 waves, 64 queries. 16 key-chunks of 64. mfma_f32_16x16x32_bf16.
// A-frag: A[m=lane&15][k=quad*8+j]; B-frag: B[k=quad*8+j][n=lane&15];
// C/D:    col=lane&15, row=quad*4+reg.
template <typename T>
__global__ __launch_bounds__(256) void attnproj_kernel(
    const bf16* __restrict__ theta, const bf16* __restrict__ phi,
    const bf16* __restrict__ g, const u16* __restrict__ waT,
    const void* xv, const void* sigv, void* outv, const int* flag) {
  if (flag[0] != io<T>::tag()) return;
  const T* xp = (const T*)xv;
  T* outp = (T*)outv;

  __shared__ u16 th_s[64][72];      //  9216 B  theta tile (pad 72: +4 banks/row)
  __shared__ u16 ph_s[64][72];      //  9216 B  phi chunk
  __shared__ u16 gt_s[256 * 72];    // 36864 B  g chunk transposed [c2][key]; later O [64][264]
  __shared__ u16 p_s[4][16][72];    //  9216 B  P tile per wave

  const int tid = threadIdx.x;
  const int w = tid >> 6;          // wave 0..3
  const int lane = tid & 63;
  const int quad = lane >> 4;      // 0..3
  const int l15 = lane & 15;
  const int bb = blockIdx.x >> 6;  // batch
  const int q0 = (blockIdx.x & 63) * 64;

  // ---- stage theta tile [64][64] ----
  {
    int r = tid >> 2, c0 = (tid & 3) * 16;
    const u16* src = (const u16*)(theta + (((size_t)bb * 4096 + q0 + r) * 64 + c0));
    *(uint4*)&th_s[r][c0] = *(const uint4*)src;
    *(uint4*)&th_s[r][c0 + 8] = *(const uint4*)(src + 8);
  }
  __syncthreads();
  const bf16x8 a0 = *(const bf16x8*)&th_s[w * 16 + l15][quad * 8];
  const bf16x8 a1 = *(const bf16x8*)&th_s[w * 16 + l15][32 + quad * 8];

  f32x4 o[16];
#pragma unroll
  for (int i = 0; i < 16; ++i) o[i] = (f32x4){0.f, 0.f, 0.f, 0.f};
  float mold[4] = {-1e30f, -1e30f, -1e30f, -1e30f};
  float lsum[4] = {0.f, 0.f, 0.f, 0.f};

  const u16* phib = (const u16*)(phi + (size_t)bb * 1024 * 64);
  const u16* gb = (const u16*)(g + (size_t)bb * 1024 * 256);

  for (int kc = 0; kc < 16; ++kc) {
    __syncthreads();               // prev chunk's ph_s/gt_s reads complete
    // stage phi chunk [64][64]
    {
      int r = tid >> 2, c0 = (tid & 3) * 16;
      const u16* src = phib + ((kc * 64 + r) * 64 + c0);
      *(uint4*)&ph_s[r][c0] = *(const uint4*)src;
      *(uint4*)&ph_s[r][c0 + 8] = *(const uint4*)(src + 8);
    }
    // stage g chunk transposed: gt_s[c2][key], 64 keys
#pragma unroll
    for (int i = 0; i < 4; ++i) {
      int id = tid + (i << 8);     // 0..1023
      int kp = id & 31;            // key pair
      int co = id >> 5;            // channel octet 0..31
      const u16* src = gb + ((kc * 64 + 2 * kp) * 256 + co * 8);
      uint4 r0 = *(const uint4*)src;
      uint4 r1 = *(const uint4*)(src + 256);
      int base = (co * 8) * 72 + 2 * kp;
      *(unsigned int*)&gt_s[base + 0 * 72] = (r0.x & 0xffffu) | (r1.x << 16);
      *(unsigned int*)&gt_s[base + 1 * 72] = (r0.x >> 16) | (r1.x & 0xffff0000u);
      *(unsigned int*)&gt_s[base + 2 * 72] = (r0.y & 0xffffu) | (r1.y << 16);
      *(unsigned int*)&gt_s[base + 3 * 72] = (r0.y >> 16) | (r1.y & 0xffff0000u);
      *(unsigned int*)&gt_s[base + 4 * 72] = (r0.z & 0xffffu) | (r1.z << 16);
      *(unsigned int*)&gt_s[base + 5 * 72] = (r0.z >> 16) | (r1.z & 0xffff0000u);
      *(unsigned int*)&gt_s[base + 6 * 72] = (r0.w & 0xffffu) | (r1.w << 16);
      *(unsigned int*)&gt_s[base + 7 * 72] = (r0.w >> 16) | (r1.w & 0xffff0000u);
    }
    __syncthreads();

    // ---- QK^T: S[16 q][64 keys] per wave ----
    f32x4 s[4];
#pragma unroll
    for (int t4 = 0; t4 < 4; ++t4) {
      bf16x8 b0 = *(const bf16x8*)&ph_s[t4 * 16 + l15][quad * 8];
      bf16x8 b1 = *(const bf16x8*)&ph_s[t4 * 16 + l15][32 + quad * 8];
      f32x4 z = (f32x4){0.f, 0.f, 0.f, 0.f};
      z = MFMA16(a0, b0, z);
      z = MFMA16(a1, b1, z);
      s[t4] = z;
    }
    // ---- online softmax (rows = quad*4+r) ----
    float rmax[4], mnew[4], alpha[4], rsum[4];
#pragma unroll
    for (int r = 0; r < 4; ++r) {
      rmax[r] = fmaxf(fmaxf(s[0][r], s[1][r]), fmaxf(s[2][r], s[3][r]));
#pragma unroll
      for (int m = 1; m <= 8; m <<= 1) rmax[r] = fmaxf(rmax[r], __shfl_xor(rmax[r], m, 64));
      mnew[r] = fmaxf(mold[r], rmax[r]);
      alpha[r] = __expf(mold[r] - mnew[r]);
      mold[r] = mnew[r];
      rsum[r] = 0.f;
    }
#pragma unroll
    for (int t4 = 0; t4 < 4; ++t4)
#pragma unroll
      for (int r = 0; r < 4; ++r) {
        float pv = __expf(s[t4][r] - mnew[r]);
        rsum[r] += pv;
        p_s[w][quad * 4 + r][t4 * 16 + l15] = f2bf_bits(pv);
      }
#pragma unroll
    for (int r = 0; r < 4; ++r) {
#pragma unroll
      for (int m = 1; m <= 8; m <<= 1) rsum[r] += __shfl_xor(rsum[r], m, 64);
      lsum[r] = lsum[r] * alpha[r] + rsum[r];
    }
#pragma unroll
    for (int i = 0; i < 16; ++i) {
      o[i][0] *= alpha[0]; o[i][1] *= alpha[1];
      o[i][2] *= alpha[2]; o[i][3] *= alpha[3];
    }
    // ---- PV: O += P @ Gchunk ----
    bf16x8 pa0 = *(const bf16x8*)&p_s[w][l15][quad * 8];
    bf16x8 pa1 = *(const bf16x8*)&p_s[w][l15][32 + quad * 8];
#pragma unroll
    for (int t4 = 0; t4 < 16; ++t4) {
      bf16x8 b0 = *(const bf16x8*)&gt_s[(t4 * 16 + l15) * 72 + quad * 8];
      bf16x8 b1 = *(const bf16x8*)&gt_s[(t4 * 16 + l15) * 72 + 32 + quad * 8];
      o[t4] = MFMA16(pa0, b0, o[t4]);
      o[t4] = MFMA16(pa1, b1, o[t4]);
    }
  }

  // ---- normalize O, store to LDS (overlay gt_s) as bf16 [64][264] ----
  __syncthreads();                 // all PV reads of gt_s done
  float inv[4];
#pragma unroll
  for (int r = 0; r < 4; ++r) inv[r] = 1.f / lsum[r];
#pragma unroll
  for (int t4 = 0; t4 < 16; ++t4)
#pragma unroll
    for (int r = 0; r < 4; ++r)
      gt_s[(w * 16 + quad * 4 + r) * 264 + t4 * 16 + l15] = f2bf_bits(o[t4][r] * inv[r]);
  // own-wave region only -> no barrier needed before reads

  float sg = io<T>::ld((const T*)sigv);
  // ---- projection O[16][256] @ waT^T -> out[16][512], two halves ----
#pragma unroll 1
  for (int h = 0; h < 2; ++h) {
    f32x4 pc[16];
#pragma unroll
    for (int i = 0; i < 16; ++i) pc[i] = (f32x4){0.f, 0.f, 0.f, 0.f};
#pragma unroll 1
    for (int ks = 0; ks < 8; ++ks) {
      bf16x8 a = *(const bf16x8*)&gt_s[(w * 16 + l15) * 264 + ks * 32 + quad * 8];
#pragma unroll
      for (int t4 = 0; t4 < 16; ++t4) {
        bf16x8 b = *(const bf16x8*)(waT + (size_t)(h * 256 + t4 * 16 + l15) * 256 + ks * 32 + quad * 8);
        pc[t4] = MFMA16(a, b, pc[t4]);
      }
    }
#pragma unroll
    for (int t4 = 0; t4 < 16; ++t4)
#pragma unroll
      for (int r = 0; r < 4; ++r) {
        int row = q0 + w * 16 + quad * 4 + r;
        int col = h * 256 + t4 * 16 + l15;
        size_t off = ((size_t)bb * 4096 + row) * 512 + col;
        io<T>::st(outp + off, io<T>::ld(xp + off) + sg * pc[t4][r]);
      }
  }
}

extern "C" void kernel_launch(void* const* d_in, const int* in_sizes, int n_in,
                              void* d_out, int out_size, void* d_ws, size_t ws_size,
                              hipStream_t stream) {
  if (ws_size < (size_t)WS_TOTAL) return;
  char* ws = (char*)d_ws;
  int*   flag  = (int*)(ws + WS_FLAG);
  float* wt    = (float*)(ws + WS_WT);
  float* wp    = (float*)(ws + WS_WP);
  float* wg    = (float*)(ws + WS_WG);
  float* wa    = (float*)(ws + WS_WA);
  bf16*  theta = (bf16*)(ws + WS_THETA);
  bf16*  phi   = (bf16*)(ws + WS_PHI);
  bf16*  g     = (bf16*)(ws + WS_G);
  u16*   waT   = (u16*)(ws + WS_WAT);

  detect_kernel<<<1, 256, 0, stream>>>(d_in[0], flag);

  sn_kernel<bf16><<<4, 256, 0, stream>>>(d_in[1], d_in[2], d_in[3], d_in[4],
                                         d_in[5], d_in[6], d_in[7], d_in[8],
                                         wt, wp, wg, wa, waT, flag);
  sn_kernel<float><<<4, 256, 0, stream>>>(d_in[1], d_in[2], d_in[3], d_in[4],
                                          d_in[5], d_in[6], d_in[7], d_in[8],
                                          wt, wp, wg, wa, waT, flag);

  conv3_kernel<bf16><<<16384, 256, 0, stream>>>(d_in[0], wt, wp, wg, theta, phi, g, flag);
  conv3_kernel<float><<<16384, 256, 0, stream>>>(d_in[0], wt, wp, wg, theta, phi, g, flag);

  attnproj_kernel<bf16><<<1024, 256, 0, stream>>>(theta, phi, g, waT, d_in[0], d_in[9], d_out, flag);
  attnproj_kernel<float><<<1024, 256, 0, stream>>>(theta, phi, g, waT, d_in[0], d_in[9], d_out, flag);
}